// Round 3
// baseline (210.398 us; speedup 1.0000x reference)
//
#include <hip/hip_runtime.h>
#include <math.h>

// N=1024, C=128, H=4, HD=32, HID=64
//   u[n,m]   = pos[n,:] @ W1[:,m]       (hid[i,j,m] = (u[i,m]+b1[m]) - u[j,m])
//   A[n,h,m] = sum_d q[n,h*32+d] * W2[m, h*32+d]
//   c[n,h]   = sum_d q[n,h*32+d] * b2[h*32+d]
//   score[h,i,j] = (q_i.k_j)/sqrt(32) + sum_m relu(hid)*A[i,h,m] + c[i,h] - dist(i,j)
//   softmax without max-subtraction (scores bounded ~[-15,+1])

static __device__ __forceinline__ float dot4(float4 a, float4 b) {
  return a.x*b.x + a.y*b.y + a.z*b.z + a.w*b.w;
}

// ---------------- K1: precompute q,k,v,u,A,c,pos4 ----------------
// grid 256 x 512 thr; block = 4 rows. W2 staged in LDS (padded) to kill the
// per-lane row-gather that dominated the old k_pre.
__global__ __launch_bounds__(512) void k_pre(
    const float* __restrict__ x, const float* __restrict__ y, const float* __restrict__ pos,
    const float* __restrict__ Wq, const float* __restrict__ bq,
    const float* __restrict__ Wk, const float* __restrict__ bk,
    const float* __restrict__ Wv, const float* __restrict__ bv,
    const float* __restrict__ W1,
    const float* __restrict__ W2, const float* __restrict__ b2,
    float* __restrict__ q, float* __restrict__ k, float* __restrict__ v,
    float* __restrict__ u, float* __restrict__ A, float* __restrict__ cvec,
    float* __restrict__ pos4w)
{
  __shared__ float xs[512], ys[512], qs[512];
  __shared__ __align__(16) float4 W2S[64*33];   // row m at [m*33 .. m*33+31], odd f4 stride

  const int t  = threadIdx.x;
  const int n0 = blockIdx.x * 4;

  // stage x, y, W2
  xs[t] = x[n0*128 + t];
  ys[t] = y[n0*128 + t];
  {
    const float4* w2g = (const float4*)W2;
    #pragma unroll
    for (int qq = 0; qq < 4; ++qq) {
      const int e = t + 512*qq;            // 0..2047
      W2S[(e>>5)*33 + (e&31)] = w2g[e];
    }
  }
  __syncthreads();

  // phase A: q,k,v (waves 0-5). waves 6-7: u and pos4.
  if (t < 384) {
    const int c   = t & 127;
    const int mat = t >> 7;                 // wave-uniform
    const float* W    = (mat == 0) ? Wq : (mat == 1 ? Wk : Wv);
    const float* S    = (mat == 0) ? xs : ys;
    const float* bias = (mat == 0) ? bq : (mat == 1 ? bk : bv);
    float a0=0.f, a1=0.f, a2=0.f, a3=0.f;
    #pragma unroll 4
    for (int d = 0; d < 128; ++d) {
      const float w_ = W[d*128 + c];
      a0 = fmaf(S[d],       w_, a0);
      a1 = fmaf(S[128 + d], w_, a1);
      a2 = fmaf(S[256 + d], w_, a2);
      a3 = fmaf(S[384 + d], w_, a3);
    }
    const float bb = bias[c];
    a0 += bb; a1 += bb; a2 += bb; a3 += bb;
    float* dst = (mat == 0) ? q : (mat == 1 ? k : v);
    dst[(n0+0)*128 + c] = a0;
    dst[(n0+1)*128 + c] = a1;
    dst[(n0+2)*128 + c] = a2;
    dst[(n0+3)*128 + c] = a3;
    if (mat == 0) { qs[c] = a0; qs[128+c] = a1; qs[256+c] = a2; qs[384+c] = a3; }
  } else {
    const int tt = t - 384;                 // 0..127
    #pragma unroll
    for (int rep = 0; rep < 2; ++rep) {
      const int e  = tt + 128*rep;          // 0..255
      const int ni = e >> 6, m = e & 63;
      float ua = 0.f;
      #pragma unroll
      for (int cc = 0; cc < 3; ++cc) ua = fmaf(pos[(n0+ni)*3 + cc], W1[cc*64 + m], ua);
      u[(n0+ni)*64 + m] = ua;
    }
    if (tt < 16) {
      const int r = tt >> 2, cm = tt & 3;
      pos4w[(n0+r)*4 + cm] = (cm < 3) ? pos[(n0+r)*3 + cm] : 0.f;
    }
  }
  __syncthreads();

  // phase B: A (all 512 threads; each does 2 rows), cvec (16 threads)
  {
    const int m   = t & 63;
    const int h   = (t >> 6) & 3;
    const int ni0 = t >> 8;                 // 0..1 -> rows ni0, ni0+2
    const float4* qs4 = (const float4*)qs;
    float acc0 = 0.f, acc1 = 0.f;
    #pragma unroll
    for (int ch = 0; ch < 8; ++ch) {
      const float4 w2 = W2S[m*33 + h*8 + ch];
      acc0 += dot4(qs4[(ni0  )*32 + h*8 + ch], w2);
      acc1 += dot4(qs4[(ni0+2)*32 + h*8 + ch], w2);
    }
    A[((n0+ni0  )*4 + h)*64 + m] = acc0;
    A[((n0+ni0+2)*4 + h)*64 + m] = acc1;
  }
  if (t < 16) {
    const int ni = t >> 2, h = t & 3;
    float ca = 0.f;
    #pragma unroll
    for (int d = 0; d < 32; ++d) ca = fmaf(qs[ni*128 + h*32 + d], b2[h*32 + d], ca);
    cvec[(n0+ni)*4 + h] = ca;
  }
}

// ---------------- K2: fused scores + softmax + PV ----------------
// grid 256 x 256 thr (4 waves). Wave w owns i-row i0+w; lane = j within a
// 64-j tile. u/k/pos j-tiles staged into LDS with coalesced loads + odd-f4
// padded strides (conflict-free b128 row reads). VGPR prefetch of tile t+1
// overlaps compute of tile t. v read from global (coalesced; L1 catches the
// 4-wave reuse). PV accumulator: one float2 per lane.
__global__ __launch_bounds__(256, 2) void k_attn(
    const float4* __restrict__ pos4,
    const float* __restrict__ q, const float* __restrict__ k, const float* __restrict__ v,
    const float* __restrict__ u, const float* __restrict__ A, const float* __restrict__ cvec,
    const float* __restrict__ b1,
    float* __restrict__ out)
{
  __shared__ __align__(16) float4 uS[64*17];   // u-tile: row r at [r*17..r*17+15]
  __shared__ __align__(16) float4 kS[64*33];   // k-tile: row r at [r*33..r*33+31]
  __shared__ __align__(16) float4 posS[64];
  __shared__ __align__(16) float qL[512];      // q rows for 4 i
  __shared__ __align__(16) float aL[1024];     // A rows for 4 i: [w][h*64+m]
  __shared__ __align__(16) float upL[256];     // (u_i + b1) for 4 i
  __shared__ float cL[16];
  __shared__ __align__(16) float eL[4*272];    // per-wave E: [w][h*68 + j]

  const int t  = threadIdx.x;
  const int i0 = blockIdx.x * 4;
  const int w    = t >> 6;
  const int lane = t & 63;

  // ---- i-data (once) ----
  qL[t]       = q[i0*128 + t];
  qL[t+256]   = q[i0*128 + 256 + t];
  #pragma unroll
  for (int qq = 0; qq < 4; ++qq) aL[t + 256*qq] = A[i0*256 + t + 256*qq];
  upL[t] = u[i0*64 + t] + b1[t & 63];
  if (t < 16) cL[t] = cvec[i0*4 + t];

  // ---- prefetch tile 0 ----
  const float4* ug = (const float4*)u;
  const float4* kg = (const float4*)k;
  float4 pu0,pu1,pu2,pu3, pk0,pk1,pk2,pk3,pk4,pk5,pk6,pk7, pp;
  {
    pu0 = ug[t]; pu1 = ug[t+256]; pu2 = ug[t+512]; pu3 = ug[t+768];
    pk0 = kg[t];      pk1 = kg[t+256];  pk2 = kg[t+512];  pk3 = kg[t+768];
    pk4 = kg[t+1024]; pk5 = kg[t+1280]; pk6 = kg[t+1536]; pk7 = kg[t+1792];
    if (t < 64) pp = pos4[t];
  }
  // write tile 0
  {
    int e;
    e = t;     uS[(e>>4)*17 + (e&15)] = pu0;
    e = t+256; uS[(e>>4)*17 + (e&15)] = pu1;
    e = t+512; uS[(e>>4)*17 + (e&15)] = pu2;
    e = t+768; uS[(e>>4)*17 + (e&15)] = pu3;
    e = t;      kS[(e>>5)*33 + (e&31)] = pk0;
    e = t+256;  kS[(e>>5)*33 + (e&31)] = pk1;
    e = t+512;  kS[(e>>5)*33 + (e&31)] = pk2;
    e = t+768;  kS[(e>>5)*33 + (e&31)] = pk3;
    e = t+1024; kS[(e>>5)*33 + (e&31)] = pk4;
    e = t+1280; kS[(e>>5)*33 + (e&31)] = pk5;
    e = t+1536; kS[(e>>5)*33 + (e&31)] = pk6;
    e = t+1792; kS[(e>>5)*33 + (e&31)] = pk7;
    if (t < 64) posS[t] = pp;
  }
  __syncthreads();

  const float4* urow = &uS[lane*17];
  const float4* krow = &kS[lane*33];
  const float4* up4  = (const float4*)&upL[w*64];
  const float4* aL4  = (const float4*)&aL[w*256];
  const float4* qL4  = (const float4*)&qL[w*128];
  const float ci0 = cL[w*4+0], ci1 = cL[w*4+1], ci2 = cL[w*4+2], ci3 = cL[w*4+3];
  const int   hl  = lane >> 4;                       // head of this lane's 2 cols
  float* eW = &eL[w*272];
  const float4* eR4 = (const float4*)&eL[w*272 + hl*68];

  float2 acc = make_float2(0.f, 0.f);
  float l0=0.f, l1=0.f, l2=0.f, l3=0.f;
  const float RS = 0.17677669529663687f;             // 1/sqrt(32)
  const float4 pi = ((const float4*)&upL[0]) ? pos4[i0 + w] : make_float4(0,0,0,0); // plain load
  const float pix = pi.x, piy = pi.y, piz = pi.z;

  for (int tt = 0; tt < 16; ++tt) {
    // prefetch tile tt+1 into regs (overlaps compute)
    if (tt < 15) {
      const float4* ugn = ug + (tt+1)*1024;
      const float4* kgn = kg + (tt+1)*2048;
      pu0 = ugn[t]; pu1 = ugn[t+256]; pu2 = ugn[t+512]; pu3 = ugn[t+768];
      pk0 = kgn[t];      pk1 = kgn[t+256];  pk2 = kgn[t+512];  pk3 = kgn[t+768];
      pk4 = kgn[t+1024]; pk5 = kgn[t+1280]; pk6 = kgn[t+1536]; pk7 = kgn[t+1792];
      if (t < 64) pp = pos4[(tt+1)*64 + t];
    }

    // ---- score my j = tt*64 + lane for my i ----
    const float4 pj = posS[lane];
    const float dx = pix - pj.x, dy = piy - pj.y, dz = piz - pj.z;
    const float dist = sqrtf(dx*dx + dy*dy + dz*dz);

    float g0 = ci0, g1 = ci1, g2 = ci2, g3 = ci3;
    #pragma unroll
    for (int mb = 0; mb < 16; ++mb) {
      const float4 uj = urow[mb];
      const float4 ub = up4[mb];
      const float h0 = fmaxf(ub.x - uj.x, 0.f);
      const float h1 = fmaxf(ub.y - uj.y, 0.f);
      const float h2 = fmaxf(ub.z - uj.z, 0.f);
      const float h3 = fmaxf(ub.w - uj.w, 0.f);
      const float4 a0 = aL4[mb], a1 = aL4[16+mb], a2 = aL4[32+mb], a3 = aL4[48+mb];
      g0 += h0*a0.x + h1*a0.y + h2*a0.z + h3*a0.w;
      g1 += h0*a1.x + h1*a1.y + h2*a1.z + h3*a1.w;
      g2 += h0*a2.x + h1*a2.y + h2*a2.z + h3*a2.w;
      g3 += h0*a3.x + h1*a3.y + h2*a3.z + h3*a3.w;
    }

    float s0=0.f, s1=0.f, s2=0.f, s3=0.f;
    #pragma unroll
    for (int cb = 0; cb < 8; ++cb) {
      s0 += dot4(krow[cb],    qL4[cb]);
      s1 += dot4(krow[8+cb],  qL4[8+cb]);
      s2 += dot4(krow[16+cb], qL4[16+cb]);
      s3 += dot4(krow[24+cb], qL4[24+cb]);
    }

    const float p0 = __expf(fmaf(s0, RS, g0) - dist);
    const float p1 = __expf(fmaf(s1, RS, g1) - dist);
    const float p2 = __expf(fmaf(s2, RS, g2) - dist);
    const float p3 = __expf(fmaf(s3, RS, g3) - dist);
    l0 += p0; l1 += p1; l2 += p2; l3 += p3;

    eW[lane] = p0; eW[68+lane] = p1; eW[136+lane] = p2; eW[204+lane] = p3;
    __builtin_amdgcn_wave_barrier();

    // ---- PV: lane owns cols 2*lane, 2*lane+1 (head hl) ----
    const float2* v2 = (const float2*)(v + (size_t)tt * 64 * 128);
    #pragma unroll
    for (int j4 = 0; j4 < 16; ++j4) {
      const float4 e4 = eR4[j4];
      const float2 v0 = v2[(j4*4+0)*64 + lane];
      const float2 v1 = v2[(j4*4+1)*64 + lane];
      const float2 v2v= v2[(j4*4+2)*64 + lane];
      const float2 v3 = v2[(j4*4+3)*64 + lane];
      acc.x = fmaf(e4.x, v0.x, acc.x);  acc.y = fmaf(e4.x, v0.y, acc.y);
      acc.x = fmaf(e4.y, v1.x, acc.x);  acc.y = fmaf(e4.y, v1.y, acc.y);
      acc.x = fmaf(e4.z, v2v.x, acc.x); acc.y = fmaf(e4.z, v2v.y, acc.y);
      acc.x = fmaf(e4.w, v3.x, acc.x);  acc.y = fmaf(e4.w, v3.y, acc.y);
    }
    __builtin_amdgcn_wave_barrier();

    __syncthreads();                 // all waves done reading tile tt
    if (tt < 15) {
      int e;
      e = t;     uS[(e>>4)*17 + (e&15)] = pu0;
      e = t+256; uS[(e>>4)*17 + (e&15)] = pu1;
      e = t+512; uS[(e>>4)*17 + (e&15)] = pu2;
      e = t+768; uS[(e>>4)*17 + (e&15)] = pu3;
      e = t;      kS[(e>>5)*33 + (e&31)] = pk0;
      e = t+256;  kS[(e>>5)*33 + (e&31)] = pk1;
      e = t+512;  kS[(e>>5)*33 + (e&31)] = pk2;
      e = t+768;  kS[(e>>5)*33 + (e&31)] = pk3;
      e = t+1024; kS[(e>>5)*33 + (e&31)] = pk4;
      e = t+1280; kS[(e>>5)*33 + (e&31)] = pk5;
      e = t+1536; kS[(e>>5)*33 + (e&31)] = pk6;
      e = t+1792; kS[(e>>5)*33 + (e&31)] = pk7;
      if (t < 64) posS[t] = pp;
      __syncthreads();               // tile tt+1 visible
    }
  }

  // ---- finalize: L per head (wave butterfly), write out ----
  #pragma unroll
  for (int mm = 1; mm < 64; mm <<= 1) {
    l0 += __shfl_xor(l0, mm);
    l1 += __shfl_xor(l1, mm);
    l2 += __shfl_xor(l2, mm);
    l3 += __shfl_xor(l3, mm);
  }
  const float L = (hl == 0) ? l0 : (hl == 1 ? l1 : (hl == 2 ? l2 : l3));
  const float inv = 1.f / L;
  float2 o; o.x = acc.x * inv; o.y = acc.y * inv;
  ((float2*)out)[(i0 + w)*64 + lane] = o;
}

extern "C" void kernel_launch(void* const* d_in, const int* in_sizes, int n_in,
                              void* d_out, int out_size, void* d_ws, size_t ws_size,
                              hipStream_t stream) {
  const float* x   = (const float*)d_in[0];
  const float* y   = (const float*)d_in[1];
  const float* pos = (const float*)d_in[2];
  const float* Wq  = (const float*)d_in[3];
  const float* bq  = (const float*)d_in[4];
  const float* Wk  = (const float*)d_in[5];
  const float* bk  = (const float*)d_in[6];
  const float* Wv  = (const float*)d_in[7];
  const float* bv  = (const float*)d_in[8];
  const float* W1  = (const float*)d_in[9];
  const float* b1  = (const float*)d_in[10];
  const float* W2  = (const float*)d_in[11];
  const float* b2  = (const float*)d_in[12];

  float* ws = (float*)d_ws;
  float* q    = ws;            // 1024*128
  float* k    = ws + 131072;   // 1024*128
  float* v    = ws + 262144;   // 1024*128
  float* u    = ws + 393216;   // 1024*64
  float* A    = ws + 458752;   // 1024*4*64
  float* cv   = ws + 720896;   // 1024*4
  float* pos4 = ws + 724992;   // 1024*4 (padded pos)
  float* out = (float*)d_out;

  k_pre<<<dim3(256), dim3(512), 0, stream>>>(x, y, pos, Wq, bq, Wk, bk, Wv, bv,
                                             W1, W2, b2, q, k, v, u, A, cv, pos4);
  k_attn<<<dim3(256), dim3(256), 0, stream>>>((const float4*)pos4, q, k, v, u, A, cv, b1, out);
}

// Round 4
// 130.164 us; speedup vs baseline: 1.6164x; 1.6164x over previous
//
#include <hip/hip_runtime.h>
#include <math.h>

// N=1024, C=128, H=4, HD=32, HID=64
//   u[n,m]   = pos[n,:] @ W1[:,m]       (hid[i,j,m] = (u[i,m]+b1[m]) - u[j,m])
//   A[n,h,m] = sum_d q[n,h*32+d] * W2[m, h*32+d]
//   c[n,h]   = sum_d q[n,h*32+d] * b2[h*32+d]
//   score[h,i,j] = (q_i.k_j)/sqrt(32) + sum_m relu(hid)*A[i,h,m] + c[i,h] - dist(i,j)
//   softmax without max-subtraction (scores bounded ~[-15,+1])
//
// ws layout (floats):
//   q    [1024][128]            (scalar-path reads in k_attn)
//   v    [1024][128]            (natural; PV float2 coalesced)
//   kT4  float4[32][1024]       kT4[cb][j] = k[j][4cb..4cb+3]  (lane=j coalesced)
//   uT4  float4[16][1024]       uT4[mb][j] = u[j][4mb..4mb+3]
//   sA   [1024][328] per-i scalar block:
//          [0..3]=c[h], [4..7]=pos_i(x,y,z,0),
//          8+mb*20+h*4+cc = A[i][h][4mb+cc], 8+mb*20+16+cc = up[i][4mb+cc]
//   pos4 [1024][4]

static __device__ __forceinline__ float dot4(float4 a, float4 b) {
  return a.x*b.x + a.y*b.y + a.z*b.z + a.w*b.w;
}

// ---------------- K1: precompute ----------------
// 512 blocks x 384 thr; block = 2 rows.
__global__ __launch_bounds__(384) void k_pre(
    const float* __restrict__ x, const float* __restrict__ y, const float* __restrict__ pos,
    const float* __restrict__ Wq, const float* __restrict__ bq,
    const float* __restrict__ Wk, const float* __restrict__ bk,
    const float* __restrict__ Wv, const float* __restrict__ bv,
    const float* __restrict__ W1, const float* __restrict__ b1,
    const float* __restrict__ W2, const float* __restrict__ b2,
    float* __restrict__ q, float* __restrict__ v,
    float* __restrict__ kT4f, float* __restrict__ uT4f,
    float* __restrict__ sA, float* __restrict__ pos4w)
{
  __shared__ float xs[256], ys[256], qs[256];
  __shared__ __align__(16) float4 W2S[64*33];   // row m at [m*33..m*33+31]

  const int t  = threadIdx.x;
  const int n0 = blockIdx.x * 2;

  if (t < 256) { xs[t] = x[n0*128 + t]; ys[t] = y[n0*128 + t]; }
  {
    const float4* w2g = (const float4*)W2;
    #pragma unroll
    for (int r = 0; r < 6; ++r) {
      const int e = t + 384*r;
      if (e < 2048) W2S[(e>>5)*33 + (e&31)] = w2g[e];
    }
  }
  __syncthreads();

  // qkv: thread = (c, mat), 2 rows each
  {
    const int c   = t & 127;
    const int mat = t >> 7;                 // wave-uniform
    const float* W    = (mat == 0) ? Wq : (mat == 1 ? Wk : Wv);
    const float* S    = (mat == 0) ? xs : ys;
    const float* bias = (mat == 0) ? bq : (mat == 1 ? bk : bv);
    float a0 = 0.f, a1 = 0.f;
    #pragma unroll 8
    for (int d = 0; d < 128; ++d) {
      const float w_ = W[d*128 + c];
      a0 = fmaf(S[d],       w_, a0);
      a1 = fmaf(S[128 + d], w_, a1);
    }
    const float bb = bias[c];
    a0 += bb; a1 += bb;
    if (mat == 0) {
      q[n0*128 + c] = a0; q[(n0+1)*128 + c] = a1;
      qs[c] = a0; qs[128 + c] = a1;
    } else if (mat == 2) {
      v[n0*128 + c] = a0; v[(n0+1)*128 + c] = a1;
    } else {
      kT4f[((c>>2)*1024 + n0  )*4 + (c&3)] = a0;
      kT4f[((c>>2)*1024 + n0+1)*4 + (c&3)] = a1;
    }
  }
  __syncthreads();

  if (t < 256) {
    // A[i][h][m] for both rows
    const int m = t & 63, h = t >> 6;
    const float4* qs4 = (const float4*)qs;
    #pragma unroll
    for (int ii = 0; ii < 2; ++ii) {
      float acc = 0.f;
      #pragma unroll
      for (int ch = 0; ch < 8; ++ch)
        acc += dot4(qs4[ii*32 + h*8 + ch], W2S[m*33 + h*8 + ch]);
      sA[(n0+ii)*328 + 8 + (m>>2)*20 + h*4 + (m&3)] = acc;
    }
    if (t < 8) {
      const int ii = t >> 2, h2 = t & 3;
      float ca = 0.f;
      #pragma unroll
      for (int d = 0; d < 32; ++d) ca = fmaf(qs[ii*128 + h2*32 + d], b2[h2*32 + d], ca);
      sA[(n0+ii)*328 + h2] = ca;
    } else if (t < 16) {
      const int tt = t-8, ii = tt>>2, cc = tt&3;
      sA[(n0+ii)*328 + 4 + cc] = (cc < 3) ? pos[(n0+ii)*3 + cc] : 0.f;
    } else if (t < 24) {
      const int tt = t-16, ii = tt>>2, cc = tt&3;
      pos4w[(n0+ii)*4 + cc] = (cc < 3) ? pos[(n0+ii)*3 + cc] : 0.f;
    }
  } else {
    // u -> uT4 + up(sA)
    const int tt = t - 256, ii = tt >> 6, m = tt & 63;
    float ua = 0.f;
    #pragma unroll
    for (int cc = 0; cc < 3; ++cc) ua = fmaf(pos[(n0+ii)*3 + cc], W1[cc*64 + m], ua);
    uT4f[((m>>2)*1024 + (n0+ii))*4 + (m&3)] = ua;
    sA[(n0+ii)*328 + 8 + (m>>2)*20 + 16 + (m&3)] = ua + b1[m];
  }
}

// ---------------- K2: fused scores + softmax + PV ----------------
// 512 blocks x 512 thr. Block = 2 i-rows; wave w covers j-tiles {2w, 2w+1},
// both i. Per-i data via scalar loads (uniform addresses -> s_load/K-cache);
// per-lane j-data via coalesced transposed global loads. No __syncthreads
// in the main loop; in-block partial reduce at the end.
__global__ __launch_bounds__(512, 2) void k_attn(
    const float* __restrict__ q, const float* __restrict__ v,
    const float4* __restrict__ kT4, const float4* __restrict__ uT4,
    const float* __restrict__ sA, const float4* __restrict__ pos4,
    float* __restrict__ out)
{
  __shared__ __align__(16) float eL[8*512];    // per-wave E: [(ii*4+h)*64 + j]
  __shared__ __align__(16) float rnum[2048];   // [w][ii][128]
  __shared__ float rden[64];                   // [w][ii][4]

  const int t    = threadIdx.x;
  const int i0   = blockIdx.x * 2;
  const int w    = t >> 6;
  const int lane = t & 63;
  const int hl   = lane >> 4;                  // head of this lane's col-pair

  const float* sA0 = sA + i0*328;              // uniform -> scalar loads
  const float* sA1 = sA0 + 328;
  const float* q0  = q + i0*128;
  const float* q1  = q0 + 128;

  const float c00 = sA0[0], c01 = sA0[1], c02 = sA0[2], c03 = sA0[3];
  const float c10 = sA1[0], c11 = sA1[1], c12 = sA1[2], c13 = sA1[3];
  const float p0x = sA0[4], p0y = sA0[5], p0z = sA0[6];
  const float p1x = sA1[4], p1y = sA1[5], p1z = sA1[6];

  float2 acc0 = make_float2(0.f, 0.f);
  float2 acc1 = make_float2(0.f, 0.f);
  float lsum[8] = {0.f,0.f,0.f,0.f,0.f,0.f,0.f,0.f};
  const float RS = 0.17677669529663687f;       // 1/sqrt(32)

  float* eW = &eL[w*512];
  const float4* er0 = (const float4*)&eL[w*512 +        hl*64];
  const float4* er1 = (const float4*)&eL[w*512 + 256 + hl*64];

  #pragma unroll
  for (int tt2 = 0; tt2 < 2; ++tt2) {
    const int jb = (w*2 + tt2) * 64;
    const int j  = jb + lane;

    const float4 pj = pos4[j];
    const float d0x = p0x-pj.x, d0y = p0y-pj.y, d0z = p0z-pj.z;
    const float d1x = p1x-pj.x, d1y = p1y-pj.y, d1z = p1z-pj.z;
    const float dist0 = sqrtf(d0x*d0x + d0y*d0y + d0z*d0z);
    const float dist1 = sqrtf(d1x*d1x + d1y*d1y + d1z*d1z);

    // ---- geom: per-lane u_j stream x per-i scalar A/up ----
    float g[2][4] = {{c00,c01,c02,c03},{c10,c11,c12,c13}};
    #pragma unroll 4
    for (int mb = 0; mb < 16; ++mb) {
      const float4 uj = uT4[mb*1024 + j];
      #pragma unroll
      for (int ii = 0; ii < 2; ++ii) {
        const float* ab = (ii ? sA1 : sA0) + 8 + mb*20;
        const float h0 = fmaxf(ab[16] - uj.x, 0.f);
        const float h1 = fmaxf(ab[17] - uj.y, 0.f);
        const float h2 = fmaxf(ab[18] - uj.z, 0.f);
        const float h3 = fmaxf(ab[19] - uj.w, 0.f);
        #pragma unroll
        for (int h = 0; h < 4; ++h)
          g[ii][h] += h0*ab[h*4+0] + h1*ab[h*4+1] + h2*ab[h*4+2] + h3*ab[h*4+3];
      }
    }

    // ---- qk: per-lane k_j stream x per-i scalar q ----
    float s[2][4] = {{0.f,0.f,0.f,0.f},{0.f,0.f,0.f,0.f}};
    #pragma unroll 8
    for (int cb = 0; cb < 32; ++cb) {
      const float4 kj = kT4[cb*1024 + j];
      const int h = cb >> 3;
      s[0][h] += kj.x*q0[cb*4+0] + kj.y*q0[cb*4+1] + kj.z*q0[cb*4+2] + kj.w*q0[cb*4+3];
      s[1][h] += kj.x*q1[cb*4+0] + kj.y*q1[cb*4+1] + kj.z*q1[cb*4+2] + kj.w*q1[cb*4+3];
    }

    // ---- softmax numerators -> wave-private E ----
    #pragma unroll
    for (int ii = 0; ii < 2; ++ii) {
      const float di = ii ? dist1 : dist0;
      #pragma unroll
      for (int h = 0; h < 4; ++h) {
        const float p = __expf(fmaf(s[ii][h], RS, g[ii][h]) - di);
        lsum[ii*4+h] += p;
        eW[(ii*4+h)*64 + lane] = p;
      }
    }
    __builtin_amdgcn_wave_barrier();

    // ---- PV: lane owns cols {2lane, 2lane+1}; v loaded once for both i ----
    const float2* v2 = (const float2*)(v + jb*128);
    #pragma unroll 4
    for (int j4 = 0; j4 < 16; ++j4) {
      const float4 e0 = er0[j4];
      const float4 e1 = er1[j4];
      const float2 va = v2[(j4*4+0)*64 + lane];
      const float2 vb = v2[(j4*4+1)*64 + lane];
      const float2 vc = v2[(j4*4+2)*64 + lane];
      const float2 vd = v2[(j4*4+3)*64 + lane];
      acc0.x = fmaf(e0.x, va.x, acc0.x); acc0.y = fmaf(e0.x, va.y, acc0.y);
      acc1.x = fmaf(e1.x, va.x, acc1.x); acc1.y = fmaf(e1.x, va.y, acc1.y);
      acc0.x = fmaf(e0.y, vb.x, acc0.x); acc0.y = fmaf(e0.y, vb.y, acc0.y);
      acc1.x = fmaf(e1.y, vb.x, acc1.x); acc1.y = fmaf(e1.y, vb.y, acc1.y);
      acc0.x = fmaf(e0.z, vc.x, acc0.x); acc0.y = fmaf(e0.z, vc.y, acc0.y);
      acc1.x = fmaf(e1.z, vc.x, acc1.x); acc1.y = fmaf(e1.z, vc.y, acc1.y);
      acc0.x = fmaf(e0.w, vd.x, acc0.x); acc0.y = fmaf(e0.w, vd.y, acc0.y);
      acc1.x = fmaf(e1.w, vd.x, acc1.x); acc1.y = fmaf(e1.w, vd.y, acc1.y);
    }
    __builtin_amdgcn_wave_barrier();
  }

  // ---- in-block reduce across waves ----
  #pragma unroll
  for (int mm = 1; mm < 64; mm <<= 1) {
    #pragma unroll
    for (int r8 = 0; r8 < 8; ++r8) lsum[r8] += __shfl_xor(lsum[r8], mm);
  }
  ((float2*)rnum)[w*128 +      lane] = acc0;
  ((float2*)rnum)[w*128 + 64 + lane] = acc1;
  if (lane == 0) {
    #pragma unroll
    for (int r8 = 0; r8 < 8; ++r8) rden[w*8 + r8] = lsum[r8];
  }
  __syncthreads();

  if (t < 256) {
    const int ii = t >> 7, c = t & 127;
    float num = 0.f, den = 0.f;
    #pragma unroll
    for (int ww = 0; ww < 8; ++ww) {
      num += rnum[ww*256 + ii*128 + c];
      den += rden[ww*8 + ii*4 + (c>>5)];
    }
    out[(i0+ii)*128 + c] = num / den;
  }
}

extern "C" void kernel_launch(void* const* d_in, const int* in_sizes, int n_in,
                              void* d_out, int out_size, void* d_ws, size_t ws_size,
                              hipStream_t stream) {
  const float* x   = (const float*)d_in[0];
  const float* y   = (const float*)d_in[1];
  const float* pos = (const float*)d_in[2];
  const float* Wq  = (const float*)d_in[3];
  const float* bq  = (const float*)d_in[4];
  const float* Wk  = (const float*)d_in[5];
  const float* bk  = (const float*)d_in[6];
  const float* Wv  = (const float*)d_in[7];
  const float* bv  = (const float*)d_in[8];
  const float* W1  = (const float*)d_in[9];
  const float* b1  = (const float*)d_in[10];
  const float* W2  = (const float*)d_in[11];
  const float* b2  = (const float*)d_in[12];

  float* ws = (float*)d_ws;
  float* q    = ws;            // 131072
  float* v    = ws + 131072;   // 131072
  float* kT4f = ws + 262144;   // 131072
  float* uT4f = ws + 393216;   // 65536
  float* sA   = ws + 458752;   // 335872
  float* pos4 = ws + 794624;   // 4096  (end: 798720 floats = 3.19 MB)
  float* out  = (float*)d_out;

  k_pre<<<dim3(512), dim3(384), 0, stream>>>(x, y, pos, Wq, bq, Wk, bk, Wv, bv,
                                             W1, b1, W2, b2,
                                             q, v, kT4f, uT4f, sA, pos4);
  k_attn<<<dim3(512), dim3(512), 0, stream>>>(q, v, (const float4*)kT4f,
                                              (const float4*)uT4f, sA,
                                              (const float4*)pos4, out);
}

// Round 5
// 117.136 us; speedup vs baseline: 1.7962x; 1.1112x over previous
//
#include <hip/hip_runtime.h>
#include <math.h>

// N=1024, C=128, H=4, HD=32, HID=64
//   u[n,m]   = pos[n,:] @ W1[:,m]       (hid[i,j,m] = (u[i,m]+b1[m]) - u[j,m])
//   A[n,h,m] = sum_d q[n,h*32+d] * W2[m, h*32+d]
//   c[n,h]   = sum_d q[n,h*32+d] * b2[h*32+d]
//   score[h,i,j] = (q_i.k_j)/sqrt(32) + sum_m relu(hid)*A[i,h,m] + c[i,h] - dist(i,j)
//   softmax via exp2: q pre-scaled by RS*log2e, A/c/pos pre-scaled by log2e
//   (softmax invariant; scores bounded ~[-22,+2] -> exp2 safe in fp32)
//
// ws layout (floats):
//   q    [1024][128]  scaled by RS*log2e (scalar-path reads in k_attn)
//   v    [1024][128]
//   kT4  float4[32][1024]   kT4[cb][j] = k[j][4cb..4cb+3]
//   uT4  float4[16][1024]   uT4[mb][j] = u[j][4mb..4mb+3]   (unscaled)
//   sA   [1024][328]: [0..3]=c[h]*L2E, [4..7]=pos_i*L2E,
//        8+mb*20+h*4+cc = A[i][h][4mb+cc]*L2E, 8+mb*20+16+cc = up[i][4mb+cc] (unscaled)
//   pos4 [1024][4] scaled by log2e

typedef float v2f __attribute__((ext_vector_type(2)));
typedef float v4f __attribute__((ext_vector_type(4)));

#define L2E 1.4426950408889634f
#define RSL (0.17677669529663687f * L2E)

static __device__ __forceinline__ float dot4(float4 a, float4 b) {
  return a.x*b.x + a.y*b.y + a.z*b.z + a.w*b.w;
}
static __device__ __forceinline__ v2f fma2(v2f a, v2f b, v2f c) {
  return __builtin_elementwise_fma(a, b, c);
}
static __device__ __forceinline__ v4f fma4s(float s, v4f b, v4f c) {
  v4f sv = {s, s, s, s};
  return __builtin_elementwise_fma(sv, b, c);
}

// ---------------- K1: precompute ----------------
// 512 blocks x 384 thr; block = 2 rows. (Same structure as R4 + scaling folds.)
__global__ __launch_bounds__(384) void k_pre(
    const float* __restrict__ x, const float* __restrict__ y, const float* __restrict__ pos,
    const float* __restrict__ Wq, const float* __restrict__ bq,
    const float* __restrict__ Wk, const float* __restrict__ bk,
    const float* __restrict__ Wv, const float* __restrict__ bv,
    const float* __restrict__ W1, const float* __restrict__ b1,
    const float* __restrict__ W2, const float* __restrict__ b2,
    float* __restrict__ q, float* __restrict__ v,
    float* __restrict__ kT4f, float* __restrict__ uT4f,
    float* __restrict__ sA, float* __restrict__ pos4w)
{
  __shared__ float xs[256], ys[256], qs[256];
  __shared__ __align__(16) float4 W2S[64*33];

  const int t  = threadIdx.x;
  const int n0 = blockIdx.x * 2;

  if (t < 256) { xs[t] = x[n0*128 + t]; ys[t] = y[n0*128 + t]; }
  {
    const float4* w2g = (const float4*)W2;
    #pragma unroll
    for (int r = 0; r < 6; ++r) {
      const int e = t + 384*r;
      if (e < 2048) W2S[(e>>5)*33 + (e&31)] = w2g[e];
    }
  }
  __syncthreads();

  {
    const int c   = t & 127;
    const int mat = t >> 7;                 // wave-uniform
    const float* W    = (mat == 0) ? Wq : (mat == 1 ? Wk : Wv);
    const float* S    = (mat == 0) ? xs : ys;
    const float* bias = (mat == 0) ? bq : (mat == 1 ? bk : bv);
    float a0 = 0.f, a1 = 0.f;
    #pragma unroll 8
    for (int d = 0; d < 128; ++d) {
      const float w_ = W[d*128 + c];
      a0 = fmaf(S[d],       w_, a0);
      a1 = fmaf(S[128 + d], w_, a1);
    }
    const float bb = bias[c];
    a0 += bb; a1 += bb;
    if (mat == 0) {
      q[n0*128 + c] = a0 * RSL; q[(n0+1)*128 + c] = a1 * RSL;
      qs[c] = a0; qs[128 + c] = a1;
    } else if (mat == 2) {
      v[n0*128 + c] = a0; v[(n0+1)*128 + c] = a1;
    } else {
      kT4f[((c>>2)*1024 + n0  )*4 + (c&3)] = a0;
      kT4f[((c>>2)*1024 + n0+1)*4 + (c&3)] = a1;
    }
  }
  __syncthreads();

  if (t < 256) {
    const int m = t & 63, h = t >> 6;
    const float4* qs4 = (const float4*)qs;
    #pragma unroll
    for (int ii = 0; ii < 2; ++ii) {
      float acc = 0.f;
      #pragma unroll
      for (int ch = 0; ch < 8; ++ch)
        acc += dot4(qs4[ii*32 + h*8 + ch], W2S[m*33 + h*8 + ch]);
      sA[(n0+ii)*328 + 8 + (m>>2)*20 + h*4 + (m&3)] = acc * L2E;
    }
    if (t < 8) {
      const int ii = t >> 2, h2 = t & 3;
      float ca = 0.f;
      #pragma unroll
      for (int d = 0; d < 32; ++d) ca = fmaf(qs[ii*128 + h2*32 + d], b2[h2*32 + d], ca);
      sA[(n0+ii)*328 + h2] = ca * L2E;
    } else if (t < 16) {
      const int tt = t-8, ii = tt>>2, cc = tt&3;
      sA[(n0+ii)*328 + 4 + cc] = (cc < 3) ? pos[(n0+ii)*3 + cc] * L2E : 0.f;
    } else if (t < 24) {
      const int tt = t-16, ii = tt>>2, cc = tt&3;
      pos4w[(n0+ii)*4 + cc] = (cc < 3) ? pos[(n0+ii)*3 + cc] * L2E : 0.f;
    }
  } else {
    const int tt = t - 256, ii = tt >> 6, m = tt & 63;
    float ua = 0.f;
    #pragma unroll
    for (int cc = 0; cc < 3; ++cc) ua = fmaf(pos[(n0+ii)*3 + cc], W1[cc*64 + m], ua);
    uT4f[((m>>2)*1024 + (n0+ii))*4 + (m&3)] = ua;
    sA[(n0+ii)*328 + 8 + (m>>2)*20 + 16 + (m&3)] = ua + b1[m];
  }
}

// ---------------- K2: fused scores + softmax + PV ----------------
// 512 blocks x 512 thr. Block = 2 i-rows; wave w covers j-tiles {2w,2w+1}.
// Per-i data via scalar loads (s_load K-cache); per-lane j-data coalesced.
// Packed fp32 math (v_pk_fma_f32) throughout the hot loops.
// PV: lane = (col-quad c4, j-half rep); E in LDS, head stride 68 (conflict-free).
__global__ __launch_bounds__(512, 4) void k_attn(
    const float* __restrict__ q, const float* __restrict__ v,
    const v4f* __restrict__ kT4, const v4f* __restrict__ uT4,
    const float* __restrict__ sA, const v4f* __restrict__ pos4,
    float* __restrict__ out)
{
  __shared__ __align__(16) float eL[8*544];    // per-wave E: [(ii*4+h)*68 + j]
  __shared__ __align__(16) float rnum[4096];   // v4f [w][ii][rep][c4]
  __shared__ float rden[64];                   // [w][ii][4]

  const int t    = threadIdx.x;
  const int i0   = blockIdx.x * 2;
  const int w    = t >> 6;
  const int lane = t & 63;
  const int c4   = lane & 31;
  const int rep  = lane >> 5;
  const int hh   = c4 >> 3;

  const float* sA0 = sA + i0*328;              // uniform -> scalar loads
  const float* sA1 = sA0 + 328;
  const float* q0  = q + i0*128;
  const float* q1  = q0 + 128;

  const float c00 = sA0[0], c01 = sA0[1], c02 = sA0[2], c03 = sA0[3];
  const float c10 = sA1[0], c11 = sA1[1], c12 = sA1[2], c13 = sA1[3];
  const float p0x = sA0[4], p0y = sA0[5], p0z = sA0[6];
  const float p1x = sA1[4], p1y = sA1[5], p1z = sA1[6];

  v4f acc0 = {0.f,0.f,0.f,0.f};
  v4f acc1 = {0.f,0.f,0.f,0.f};
  float lsum[8] = {0.f,0.f,0.f,0.f,0.f,0.f,0.f,0.f};

  float* eW = &eL[w*544];
  const v4f* er0 = (const v4f*)&eL[w*544 +  hh     *68 + rep*32];
  const v4f* er1 = (const v4f*)&eL[w*544 + (4+hh)  *68 + rep*32];

  #pragma unroll
  for (int tt2 = 0; tt2 < 2; ++tt2) {
    const int jb = (w*2 + tt2) * 64;
    const int j  = jb + lane;

    const v4f pj = pos4[j];
    const float d0x = p0x-pj.x, d0y = p0y-pj.y, d0z = p0z-pj.z;
    const float d1x = p1x-pj.x, d1y = p1y-pj.y, d1z = p1z-pj.z;
    const float dist0 = sqrtf(d0x*d0x + d0y*d0y + d0z*d0z);
    const float dist1 = sqrtf(d1x*d1x + d1y*d1y + d1z*d1z);

    // ---- geom (packed): per-lane u_j stream x per-i scalar A/up ----
    v2f g0a={0.f,0.f}, g0b={0.f,0.f}, g0c={0.f,0.f}, g0d={0.f,0.f};
    v2f g1a={0.f,0.f}, g1b={0.f,0.f}, g1c={0.f,0.f}, g1d={0.f,0.f};
    #pragma unroll 4
    for (int mb = 0; mb < 16; ++mb) {
      const v4f uj = uT4[mb*1024 + j];
      const v2f uj01 = uj.xy, uj23 = uj.zw;
      {
        const float* ab = sA0 + 8 + mb*20;
        const v2f z = {0.f, 0.f};
        const v2f h01 = __builtin_elementwise_max(*(const v2f*)(ab+16) - uj01, z);
        const v2f h23 = __builtin_elementwise_max(*(const v2f*)(ab+18) - uj23, z);
        g0a = fma2(h01, *(const v2f*)(ab+ 0), g0a); g0a = fma2(h23, *(const v2f*)(ab+ 2), g0a);
        g0b = fma2(h01, *(const v2f*)(ab+ 4), g0b); g0b = fma2(h23, *(const v2f*)(ab+ 6), g0b);
        g0c = fma2(h01, *(const v2f*)(ab+ 8), g0c); g0c = fma2(h23, *(const v2f*)(ab+10), g0c);
        g0d = fma2(h01, *(const v2f*)(ab+12), g0d); g0d = fma2(h23, *(const v2f*)(ab+14), g0d);
      }
      {
        const float* ab = sA1 + 8 + mb*20;
        const v2f z = {0.f, 0.f};
        const v2f h01 = __builtin_elementwise_max(*(const v2f*)(ab+16) - uj01, z);
        const v2f h23 = __builtin_elementwise_max(*(const v2f*)(ab+18) - uj23, z);
        g1a = fma2(h01, *(const v2f*)(ab+ 0), g1a); g1a = fma2(h23, *(const v2f*)(ab+ 2), g1a);
        g1b = fma2(h01, *(const v2f*)(ab+ 4), g1b); g1b = fma2(h23, *(const v2f*)(ab+ 6), g1b);
        g1c = fma2(h01, *(const v2f*)(ab+ 8), g1c); g1c = fma2(h23, *(const v2f*)(ab+10), g1c);
        g1d = fma2(h01, *(const v2f*)(ab+12), g1d); g1d = fma2(h23, *(const v2f*)(ab+14), g1d);
      }
    }

    // ---- qk (packed): per-lane k_j stream x per-i scalar q ----
    v2f s0a={0.f,0.f}, s0b={0.f,0.f}, s0c={0.f,0.f}, s0d={0.f,0.f};
    v2f s1a={0.f,0.f}, s1b={0.f,0.f}, s1c={0.f,0.f}, s1d={0.f,0.f};
    #pragma unroll 8
    for (int cb = 0; cb < 8; ++cb) {
      const v4f k0 = kT4[(cb     )*1024 + j];
      const v4f k1 = kT4[(cb +  8)*1024 + j];
      const v4f k2 = kT4[(cb + 16)*1024 + j];
      const v4f k3 = kT4[(cb + 24)*1024 + j];
      s0a = fma2(k0.xy, *(const v2f*)(q0 + cb*4      ), s0a); s0a = fma2(k0.zw, *(const v2f*)(q0 + cb*4 +  2), s0a);
      s0b = fma2(k1.xy, *(const v2f*)(q0 + cb*4 + 32 ), s0b); s0b = fma2(k1.zw, *(const v2f*)(q0 + cb*4 + 34), s0b);
      s0c = fma2(k2.xy, *(const v2f*)(q0 + cb*4 + 64 ), s0c); s0c = fma2(k2.zw, *(const v2f*)(q0 + cb*4 + 66), s0c);
      s0d = fma2(k3.xy, *(const v2f*)(q0 + cb*4 + 96 ), s0d); s0d = fma2(k3.zw, *(const v2f*)(q0 + cb*4 + 98), s0d);
      s1a = fma2(k0.xy, *(const v2f*)(q1 + cb*4      ), s1a); s1a = fma2(k0.zw, *(const v2f*)(q1 + cb*4 +  2), s1a);
      s1b = fma2(k1.xy, *(const v2f*)(q1 + cb*4 + 32 ), s1b); s1b = fma2(k1.zw, *(const v2f*)(q1 + cb*4 + 34), s1b);
      s1c = fma2(k2.xy, *(const v2f*)(q1 + cb*4 + 64 ), s1c); s1c = fma2(k2.zw, *(const v2f*)(q1 + cb*4 + 66), s1c);
      s1d = fma2(k3.xy, *(const v2f*)(q1 + cb*4 + 96 ), s1d); s1d = fma2(k3.zw, *(const v2f*)(q1 + cb*4 + 98), s1d);
    }

    // ---- softmax numerators (exp2; all terms pre-scaled by log2e) ----
    {
      const v2f t0a = s0a + g0a, t0b = s0b + g0b, t0c = s0c + g0c, t0d = s0d + g0d;
      const float p0 = exp2f(t0a.x + t0a.y + (c00 - dist0));
      const float p1 = exp2f(t0b.x + t0b.y + (c01 - dist0));
      const float p2 = exp2f(t0c.x + t0c.y + (c02 - dist0));
      const float p3 = exp2f(t0d.x + t0d.y + (c03 - dist0));
      lsum[0] += p0; lsum[1] += p1; lsum[2] += p2; lsum[3] += p3;
      eW[      lane] = p0; eW[ 68 + lane] = p1; eW[136 + lane] = p2; eW[204 + lane] = p3;
      const v2f t1a = s1a + g1a, t1b = s1b + g1b, t1c = s1c + g1c, t1d = s1d + g1d;
      const float r0 = exp2f(t1a.x + t1a.y + (c10 - dist1));
      const float r1 = exp2f(t1b.x + t1b.y + (c11 - dist1));
      const float r2 = exp2f(t1c.x + t1c.y + (c12 - dist1));
      const float r3 = exp2f(t1d.x + t1d.y + (c13 - dist1));
      lsum[4] += r0; lsum[5] += r1; lsum[6] += r2; lsum[7] += r3;
      eW[272 + lane] = r0; eW[340 + lane] = r1; eW[408 + lane] = r2; eW[476 + lane] = r3;
    }
    __builtin_amdgcn_wave_barrier();

    // ---- PV: lane owns col-quad c4, rep = j-half; packed fma4 ----
    const v4f* vg = (const v4f*)(v + jb*128);
    const int vbase = rep*32*32 + c4;
    #pragma unroll 4
    for (int jj4 = 0; jj4 < 8; ++jj4) {
      const v4f e0 = er0[jj4];
      const v4f e1 = er1[jj4];
      const v4f va = vg[vbase + (jj4*4+0)*32];
      const v4f vb = vg[vbase + (jj4*4+1)*32];
      const v4f vc = vg[vbase + (jj4*4+2)*32];
      const v4f vd = vg[vbase + (jj4*4+3)*32];
      acc0 = fma4s(e0.x, va, acc0); acc1 = fma4s(e1.x, va, acc1);
      acc0 = fma4s(e0.y, vb, acc0); acc1 = fma4s(e1.y, vb, acc1);
      acc0 = fma4s(e0.z, vc, acc0); acc1 = fma4s(e1.z, vc, acc1);
      acc0 = fma4s(e0.w, vd, acc0); acc1 = fma4s(e1.w, vd, acc1);
    }
    __builtin_amdgcn_wave_barrier();
  }

  // ---- in-block reduce ----
  #pragma unroll
  for (int mm = 1; mm < 64; mm <<= 1) {
    #pragma unroll
    for (int r8 = 0; r8 < 8; ++r8) lsum[r8] += __shfl_xor(lsum[r8], mm);
  }
  ((v4f*)rnum)[((w*2+0)*2 + rep)*32 + c4] = acc0;
  ((v4f*)rnum)[((w*2+1)*2 + rep)*32 + c4] = acc1;
  if (lane == 0) {
    #pragma unroll
    for (int r8 = 0; r8 < 8; ++r8) rden[w*8 + r8] = lsum[r8];
  }
  __syncthreads();

  if (t < 256) {
    const int ii = t >> 7, c = t & 127;
    float num = 0.f, den = 0.f;
    #pragma unroll
    for (int ww = 0; ww < 8; ++ww) {
      num += rnum[((ww*2+ii)*2+0)*128 + c] + rnum[((ww*2+ii)*2+1)*128 + c];
      den += rden[ww*8 + ii*4 + (c>>5)];
    }
    out[(i0+ii)*128 + c] = num / den;
  }
}

extern "C" void kernel_launch(void* const* d_in, const int* in_sizes, int n_in,
                              void* d_out, int out_size, void* d_ws, size_t ws_size,
                              hipStream_t stream) {
  const float* x   = (const float*)d_in[0];
  const float* y   = (const float*)d_in[1];
  const float* pos = (const float*)d_in[2];
  const float* Wq  = (const float*)d_in[3];
  const float* bq  = (const float*)d_in[4];
  const float* Wk  = (const float*)d_in[5];
  const float* bk  = (const float*)d_in[6];
  const float* Wv  = (const float*)d_in[7];
  const float* bv  = (const float*)d_in[8];
  const float* W1  = (const float*)d_in[9];
  const float* b1  = (const float*)d_in[10];
  const float* W2  = (const float*)d_in[11];
  const float* b2  = (const float*)d_in[12];

  float* ws = (float*)d_ws;
  float* q    = ws;            // 131072
  float* v    = ws + 131072;   // 131072
  float* kT4f = ws + 262144;   // 131072
  float* uT4f = ws + 393216;   // 65536
  float* sA   = ws + 458752;   // 335872
  float* pos4 = ws + 794624;   // 4096
  float* out  = (float*)d_out;

  k_pre<<<dim3(512), dim3(384), 0, stream>>>(x, y, pos, Wq, bq, Wk, bk, Wv, bv,
                                             W1, b1, W2, b2,
                                             q, v, kT4f, uT4f, sA, pos4);
  k_attn<<<dim3(512), dim3(512), 0, stream>>>(q, v, (const v4f*)kT4f,
                                              (const v4f*)uT4f, sA,
                                              (const v4f*)pos4, out);
}